// Round 4
// baseline (679.896 us; speedup 1.0000x reference)
//
#include <hip/hip_runtime.h>
#include <cstdio>

typedef __bf16 bf16;
typedef __bf16 bf16x8 __attribute__((ext_vector_type(8)));
typedef __bf16 bf16x4 __attribute__((ext_vector_type(4)));
typedef float floatx4 __attribute__((ext_vector_type(4)));

#define T_TOK 4096
#define Dm    1024
#define Hm    512
#define Em    32
#define HsDim 1024   // shared inter dim
#define Pp    16384  // T*K pairs
#define CAP   2048   // per-expert capacity

// ---------------------------------------------------------------- gate ------
// logits[t][e] = x[t][:] . Wg[:][e] in fp32 (must match reference routing).
// 8 tokens/block; also writes the bf16 cast of x (x rows already in LDS).
__global__ __launch_bounds__(256) void gate_logits(
    const float* __restrict__ xf, const float* __restrict__ Wg,
    float* __restrict__ logits, bf16* __restrict__ xb)
{
    __shared__ float xs[8][Dm];        // 32 KB
    __shared__ float wsC[128 * Em];    // 16 KB, natural [d][e] layout
    int tid = threadIdx.x;
    int t0 = blockIdx.x * 8;

    const float4* src = (const float4*)(xf + (size_t)t0 * Dm);
    float4* dst = (float4*)&xs[0][0];
#pragma unroll
    for (int i = 0; i < 8; ++i) dst[tid + i * 256] = src[tid + i * 256];

    int tg = tid >> 5, e = tid & 31;
    float acc = 0.f;
    for (int d0 = 0; d0 < Dm; d0 += 128) {
        __syncthreads();               // covers xs on iter 0, wsC reuse after
        const float4* wg4 = (const float4*)(Wg + (size_t)d0 * Em);
        float4* ws4 = (float4*)wsC;
#pragma unroll
        for (int i = 0; i < 4; ++i) ws4[tid + i * 256] = wg4[tid + i * 256];
        __syncthreads();
#pragma unroll
        for (int d = 0; d < 128; d += 4) {
            float4 xv = *(const float4*)&xs[tg][d0 + d];
            acc = fmaf(xv.x, wsC[(d + 0) * Em + e], acc);
            acc = fmaf(xv.y, wsC[(d + 1) * Em + e], acc);
            acc = fmaf(xv.z, wsC[(d + 2) * Em + e], acc);
            acc = fmaf(xv.w, wsC[(d + 3) * Em + e], acc);
        }
    }
    logits[(size_t)(t0 + tg) * Em + e] = acc;

    // bf16 cast of the 8 staged rows (xs unchanged since load; already synced)
    bf16x4* xbrow = (bf16x4*)(xb + (size_t)t0 * Dm);
    const float4* xsf = (const float4*)&xs[0][0];
#pragma unroll
    for (int i = 0; i < 8; ++i) {
        int idx = tid + i * 256;
        float4 v = xsf[idx];
        bf16x4 o = {(bf16)v.x, (bf16)v.y, (bf16)v.z, (bf16)v.w};
        xbrow[idx] = o;
    }
}

// Per-token softmax + stable top-4 (ties -> lower index, same as lax.top_k).
__global__ __launch_bounds__(256) void gate_topk(
    const float* __restrict__ logits, int* __restrict__ topk_e,
    float* __restrict__ topk_w, int* __restrict__ cnt)
{
    __shared__ int hist[Em];
    int tid = threadIdx.x;
    if (tid < Em) hist[tid] = 0;
    __syncthreads();

    int t = blockIdx.x * 256 + tid;
    float l[Em];
    float M = -3.0e38f;
#pragma unroll
    for (int i = 0; i < 8; ++i) {
        float4 v = *(const float4*)(logits + (size_t)t * Em + i * 4);
        l[i * 4 + 0] = v.x; l[i * 4 + 1] = v.y;
        l[i * 4 + 2] = v.z; l[i * 4 + 3] = v.w;
        M = fmaxf(M, fmaxf(fmaxf(v.x, v.y), fmaxf(v.z, v.w)));
    }
    float sum = 0.f;
#pragma unroll
    for (int i = 0; i < Em; ++i) sum += __expf(l[i] - M);
    float inv = 1.0f / sum;
#pragma unroll
    for (int k = 0; k < 4; ++k) {
        float best = -3.0e38f; int bi = 0;
#pragma unroll
        for (int i = 0; i < Em; ++i)
            if (l[i] > best) { best = l[i]; bi = i; }
        topk_e[t * 4 + k] = bi;
        topk_w[t * 4 + k] = __expf(best - M) * inv;
        atomicAdd(&hist[bi], 1);
#pragma unroll
        for (int i = 0; i < Em; ++i)
            if (i == bi) l[i] = -3.0e38f;
    }
    __syncthreads();
    if (tid < Em) { int h = hist[tid]; if (h) atomicAdd(&cnt[tid], h); }
}

__global__ void offsets_kernel(const int* __restrict__ cnt, int* __restrict__ cntc,
                               int* __restrict__ offs)
{
    if (threadIdx.x == 0) {
        int run = 0;
        for (int e = 0; e < Em; ++e) {
            int c = cnt[e]; if (c > CAP) c = CAP;
            cntc[e] = c; offs[e] = run; run += c;
        }
        offs[Em] = run;
    }
}

// Records pair -> compact-row map (posC, -1 = capacity-dropped).
__global__ void scatter_kernel(const int* __restrict__ topk_e, const float* __restrict__ topk_w,
                               const int* __restrict__ cntc, const int* __restrict__ offs,
                               int* __restrict__ cnt2, int* __restrict__ tok_c,
                               float* __restrict__ wt_c, int* __restrict__ posC)
{
    int p = blockIdx.x * 256 + threadIdx.x;
    if (p >= Pp) return;
    int e = topk_e[p];
    int slot = atomicAdd(&cnt2[e], 1);
    int rc = -1;
    if (slot < cntc[e]) {
        rc = offs[e] + slot;
        tok_c[rc] = p >> 2;
        wt_c[rc] = topk_w[p];
    }
    posC[p] = rc;
}

// ---------------------------------------------------------------- casts -----
// 64x64 tile fp32->bf16 transpose. src batch b: (R x Cc) row-major at
// src + b*sstride -> dst (Cc x R) row-major at dst + b*dstride.
// Block (64,4). Reads 256B/wave contiguous; LDS reads 2-way aliased (free).
__device__ __forceinline__ void transpose_tile64(
    const float* __restrict__ src, bf16* __restrict__ dst, int R, int Cc)
{
    __shared__ float t[64][65];
    int r0 = blockIdx.y * 64, c0 = blockIdx.x * 64;
    int tx = threadIdx.x, ty = threadIdx.y;
#pragma unroll
    for (int i = 0; i < 16; ++i) {
        int row = ty + i * 4;
        t[row][tx] = src[(long)(r0 + row) * Cc + (c0 + tx)];
    }
    __syncthreads();
#pragma unroll
    for (int i = 0; i < 16; ++i) {
        int row = ty + i * 4;
        dst[(long)(c0 + row) * R + (r0 + tx)] = (bf16)t[tx][row];
    }
}

// W1 (z<32) and W3 (z>=32): (Dm x Hm) -> rows [0,512) / [512,1024) of the
// per-expert 1024 x Dm block of W13T.
__global__ __launch_bounds__(256) void transpose_w13(
    const float* __restrict__ W1, const float* __restrict__ W3,
    bf16* __restrict__ W13T)
{
    int z = blockIdx.z;
    int e = z & 31;
    const float* src = (z < 32 ? W1 : W3) + (long)e * Dm * Hm;
    bf16* dst = W13T + (long)e * 2 * Hm * Dm + (z < 32 ? 0 : (long)Hm * Dm);
    transpose_tile64(src, dst, Dm, Hm);
}

// W2[e]: (Hm x Dm) -> (Dm x Hm)
__global__ __launch_bounds__(256) void transpose_w2(
    const float* __restrict__ W2, bf16* __restrict__ W2T)
{
    int e = blockIdx.z;
    transpose_tile64(W2 + (long)e * Hm * Dm, W2T + (long)e * Hm * Dm, Hm, Dm);
}

// Ws1 / Ws3 / Ws2, each (1024 x 1024), selected by z.
__global__ __launch_bounds__(256) void transpose_ws(
    const float* __restrict__ Ws1, const float* __restrict__ Ws3,
    const float* __restrict__ Ws2, bf16* __restrict__ Ws13T,
    bf16* __restrict__ Ws2T)
{
    int z = blockIdx.z;
    const float* src = z == 0 ? Ws1 : (z == 1 ? Ws3 : Ws2);
    bf16* dst = z == 0 ? Ws13T : (z == 1 ? Ws13T + (long)HsDim * Dm : Ws2T);
    transpose_tile64(src, dst, Dm, Dm);
}

// ---------------------------------------------------------------- GEMM ------
// 128x128 tile, BK=64, 4 waves (64x64 each), mfma_f32_16x16x32_bf16,
// global_load_lds width-16, XOR-swizzled LDS chunks.
__device__ __forceinline__ void gload_lds16(const bf16* g, bf16* l)
{
    __builtin_amdgcn_global_load_lds((const __attribute__((address_space(1))) void*)g,
                                     (__attribute__((address_space(3))) void*)l, 16, 0, 0);
}

// Merged GEMM1 (+fused SwiGLU): blockIdx.y < 512 -> routed experts
// (e = y>>4, gathered A rows, W13T, out Hh ld 512, 4 n-tiles);
// y >= 512 -> shared experts (Ws13T, out HhS ld 1024, 8 n-tiles).
__global__ void __launch_bounds__(256, 3) gemm1_merged(
    const bf16* __restrict__ xb, const bf16* __restrict__ W13T,
    const bf16* __restrict__ Ws13T,
    const int* __restrict__ cntc, const int* __restrict__ offs,
    const int* __restrict__ tok,
    bf16* __restrict__ Hh, bf16* __restrict__ HhS)
{
    __shared__ __align__(16) bf16 As[128 * 64];
    __shared__ __align__(16) bf16 B1[128 * 64];
    __shared__ __align__(16) bf16 B3[128 * 64];

    int y = blockIdx.y, nt = blockIdx.x;
    int mt, mcount, rowbase;
    const bf16* BT;
    bf16* outH;
    int ldo;
    long off3;
    bool gather;
    if (y < 512) {
        if (nt >= 4) return;               // expert N = 512 -> 4 n-tiles
        int e = y >> 4;
        mt = y & 15;
        mcount = cntc[e];
        if (mt * 128 >= mcount) return;
        rowbase = offs[e];
        BT = W13T + (long)e * 2 * Hm * Dm;
        outH = Hh; ldo = Hm; off3 = (long)Hm * Dm;
        gather = true;
    } else {
        mt = y - 512; mcount = T_TOK; rowbase = 0;
        BT = Ws13T;
        outH = HhS; ldo = HsDim; off3 = (long)HsDim * Dm;
        gather = false;
    }

    int tid = threadIdx.x;
    int wave = tid >> 6, lane = tid & 63;
    int wm = wave >> 1, wn = wave & 1;
    int q = lane >> 4, lm = lane & 15;

    floatx4 acc1[4][4] = {};
    floatx4 acc3[4][4] = {};

    const bf16* arow[4];
    const bf16* brow[4];
#pragma unroll
    for (int it = 0; it < 4; ++it) {
        int c = wave * 256 + it * 64 + lane;
        int row = c >> 3;
        int kc = (c & 7) ^ (row & 7);      // XOR swizzle on 16B chunks
        int rl = mt * 128 + row;
        int rr = rl < mcount ? rl : mcount - 1;
        long aoff;
        if (gather) aoff = (long)tok[rowbase + rr] * Dm;
        else        aoff = (long)rr * Dm;
        arow[it] = xb + aoff + kc * 8;
        brow[it] = BT + (long)(nt * 128 + row) * Dm + kc * 8;
    }

    for (int kt = 0; kt < Dm; kt += 64) {
#pragma unroll
        for (int it = 0; it < 4; ++it)
            gload_lds16(arow[it] + kt, As + (wave * 256 + it * 64) * 8);
#pragma unroll
        for (int it = 0; it < 4; ++it)
            gload_lds16(brow[it] + kt, B1 + (wave * 256 + it * 64) * 8);
#pragma unroll
        for (int it = 0; it < 4; ++it)
            gload_lds16(brow[it] + off3 + kt, B3 + (wave * 256 + it * 64) * 8);
        __syncthreads();
#pragma unroll
        for (int kk = 0; kk < 2; ++kk) {
            bf16x8 af[4], b1v[4], b3v[4];
            int j = kk * 4 + q;
#pragma unroll
            for (int i = 0; i < 4; ++i) {
                int row = wm * 64 + i * 16 + lm;
                af[i] = *(const bf16x8*)(As + row * 64 + ((j ^ (row & 7)) * 8));
            }
#pragma unroll
            for (int j2 = 0; j2 < 4; ++j2) {
                int row = wn * 64 + j2 * 16 + lm;
                b1v[j2] = *(const bf16x8*)(B1 + row * 64 + ((j ^ (row & 7)) * 8));
                b3v[j2] = *(const bf16x8*)(B3 + row * 64 + ((j ^ (row & 7)) * 8));
            }
#pragma unroll
            for (int i = 0; i < 4; ++i)
#pragma unroll
                for (int j2 = 0; j2 < 4; ++j2) {
                    acc1[i][j2] = __builtin_amdgcn_mfma_f32_16x16x32_bf16(
                        af[i], b1v[j2], acc1[i][j2], 0, 0, 0);
                    acc3[i][j2] = __builtin_amdgcn_mfma_f32_16x16x32_bf16(
                        af[i], b3v[j2], acc3[i][j2], 0, 0, 0);
                }
        }
        __syncthreads();
    }

    int colbase = nt * 128 + wn * 64;
#pragma unroll
    for (int i = 0; i < 4; ++i) {
        int rloc = wm * 64 + i * 16 + q * 4;
#pragma unroll
        for (int r = 0; r < 4; ++r) {
            int rl = mt * 128 + rloc + r;
            if (rl >= mcount) continue;
#pragma unroll
            for (int j2 = 0; j2 < 4; ++j2) {
                int col = colbase + j2 * 16 + lm;
                float a = acc1[i][j2][r], b = acc3[i][j2][r];
                float sg = 1.0f / (1.0f + __expf(-a));
                outH[(long)(rowbase + rl) * ldo + col] = (bf16)(a * sg * b);
            }
        }
    }
}

// Merged GEMM2: y < 512 -> expert (A=Hh K=512, B=W2T[e], bf16 compact store
// to Yc); y >= 512 -> shared (A=HhS K=1024, B=Ws2T, fp32 store to out).
__global__ void __launch_bounds__(256, 4) gemm2_merged(
    const bf16* __restrict__ Hh, const bf16* __restrict__ HhS,
    const bf16* __restrict__ W2T, const bf16* __restrict__ Ws2T,
    const int* __restrict__ cntc, const int* __restrict__ offs,
    bf16* __restrict__ Yc, float* __restrict__ out)
{
    __shared__ __align__(16) bf16 As[128 * 64];
    __shared__ __align__(16) bf16 Bs[128 * 64];

    int y = blockIdx.y, nt = blockIdx.x;
    int mt, mcount, rowbase, K, lda;
    const bf16* A;
    const bf16* BT;
    bool toBf;
    if (y < 512) {
        int e = y >> 4;
        mt = y & 15;
        mcount = cntc[e];
        if (mt * 128 >= mcount) return;
        rowbase = offs[e];
        A = Hh; lda = Hm; K = Hm;
        BT = W2T + (long)e * Hm * Dm;
        toBf = true;
    } else {
        mt = y - 512; mcount = T_TOK; rowbase = 0;
        A = HhS; lda = HsDim; K = HsDim;
        BT = Ws2T;
        toBf = false;
    }

    int tid = threadIdx.x;
    int wave = tid >> 6, lane = tid & 63;
    int wm = wave >> 1, wn = wave & 1;
    int q = lane >> 4, lm = lane & 15;

    floatx4 acc[4][4] = {};

    const bf16* arow[4];
    const bf16* brow[4];
#pragma unroll
    for (int it = 0; it < 4; ++it) {
        int c = wave * 256 + it * 64 + lane;
        int row = c >> 3;
        int kc = (c & 7) ^ (row & 7);
        int rl = mt * 128 + row;
        int rr = rl < mcount ? rl : mcount - 1;
        arow[it] = A + (long)(rowbase + rr) * lda + kc * 8;
        brow[it] = BT + (long)(nt * 128 + row) * K + kc * 8;
    }

    for (int kt = 0; kt < K; kt += 64) {
#pragma unroll
        for (int it = 0; it < 4; ++it)
            gload_lds16(arow[it] + kt, As + (wave * 256 + it * 64) * 8);
#pragma unroll
        for (int it = 0; it < 4; ++it)
            gload_lds16(brow[it] + kt, Bs + (wave * 256 + it * 64) * 8);
        __syncthreads();
#pragma unroll
        for (int kk = 0; kk < 2; ++kk) {
            bf16x8 af[4], bfv[4];
            int j = kk * 4 + q;
#pragma unroll
            for (int i = 0; i < 4; ++i) {
                int row = wm * 64 + i * 16 + lm;
                af[i] = *(const bf16x8*)(As + row * 64 + ((j ^ (row & 7)) * 8));
            }
#pragma unroll
            for (int j2 = 0; j2 < 4; ++j2) {
                int row = wn * 64 + j2 * 16 + lm;
                bfv[j2] = *(const bf16x8*)(Bs + row * 64 + ((j ^ (row & 7)) * 8));
            }
#pragma unroll
            for (int i = 0; i < 4; ++i)
#pragma unroll
                for (int j2 = 0; j2 < 4; ++j2)
                    acc[i][j2] = __builtin_amdgcn_mfma_f32_16x16x32_bf16(
                        af[i], bfv[j2], acc[i][j2], 0, 0, 0);
        }
        __syncthreads();
    }

    int colbase = nt * 128 + wn * 64;
#pragma unroll
    for (int i = 0; i < 4; ++i) {
        int rloc = wm * 64 + i * 16 + q * 4;
#pragma unroll
        for (int r = 0; r < 4; ++r) {
            int rl = mt * 128 + rloc + r;
            if (rl >= mcount) continue;
#pragma unroll
            for (int j2 = 0; j2 < 4; ++j2) {
                int col = colbase + j2 * 16 + lm;
                float v = acc[i][j2][r];
                if (toBf) Yc[(long)(rowbase + rl) * Dm + col] = (bf16)v;
                else      out[(long)rl * Dm + col] = v;
            }
        }
    }
}

// ------------------------------------------------------------- combine ------
// out[t][:] += sum_k w[t,k] * Yc[posC[t*4+k]][:]  (posC<0 => dropped pair).
__global__ __launch_bounds__(256) void combine_kernel(
    const bf16* __restrict__ Yc, const float* __restrict__ topkW,
    const int* __restrict__ posC, float* __restrict__ out)
{
    __shared__ int   sp[4];
    __shared__ float sw[4];
    int t = blockIdx.x, tid = threadIdx.x;
    if (tid < 4) {
        sp[tid] = posC[t * 4 + tid];
        sw[tid] = topkW[t * 4 + tid];
    }
    __syncthreads();
    int d = tid * 4;
    float4 o = *(float4*)(out + (size_t)t * Dm + d);
#pragma unroll
    for (int k = 0; k < 4; ++k) {
        int rc = sp[k];
        if (rc >= 0) {
            bf16x4 v = *(const bf16x4*)(Yc + (size_t)rc * Dm + d);
            float w = sw[k];
            o.x += w * (float)v[0];
            o.y += w * (float)v[1];
            o.z += w * (float)v[2];
            o.w += w * (float)v[3];
        }
    }
    *(float4*)(out + (size_t)t * Dm + d) = o;
}

// ---------------------------------------------------------------- launch ----
extern "C" void kernel_launch(void* const* d_in, const int* in_sizes, int n_in,
                              void* d_out, int out_size, void* d_ws, size_t ws_size,
                              hipStream_t stream)
{
    const float* x   = (const float*)d_in[0];
    const float* Wg  = (const float*)d_in[1];
    const float* W1  = (const float*)d_in[2];
    const float* W2  = (const float*)d_in[3];
    const float* W3  = (const float*)d_in[4];
    const float* Ws1 = (const float*)d_in[5];
    const float* Ws2 = (const float*)d_in[6];
    const float* Ws3 = (const float*)d_in[7];
    float* out = (float*)d_out;

    char* p = (char*)d_ws;
    auto alloc = [&](size_t bytes) {
        char* r = p; p += (bytes + 255) & ~(size_t)255; return r;
    };
    bf16*  xb    = (bf16*)alloc((size_t)T_TOK * Dm * 2);
    bf16*  W13T  = (bf16*)alloc((size_t)Em * 2 * Hm * Dm * 2);
    bf16*  W2T   = (bf16*)alloc((size_t)Em * Dm * Hm * 2);
    bf16*  Ws13T = (bf16*)alloc((size_t)2 * HsDim * Dm * 2);
    bf16*  Ws2T  = (bf16*)alloc((size_t)Dm * HsDim * 2);
    bf16*  Yc    = (bf16*)alloc((size_t)Pp * Dm * 2);      // expert GEMM2 compact out
    bf16*  Hh    = (bf16*)alloc((size_t)Pp * Hm * 2);      // expert hidden (compact)
    bf16*  HhS   = (bf16*)alloc((size_t)T_TOK * HsDim * 2);// shared hidden
    float* logits= (float*)alloc((size_t)T_TOK * Em * 4);
    int*   topkE = (int*)alloc(Pp * 4);
    float* topkW = (float*)alloc(Pp * 4);
    int*   tokC  = (int*)alloc(Pp * 4);
    float* wtC   = (float*)alloc(Pp * 4);
    int*   posC  = (int*)alloc(Pp * 4);
    int*   cnt   = (int*)alloc(128);
    int*   cnt2  = (int*)alloc(128);
    int*   cntc  = (int*)alloc(128);
    int*   offs  = (int*)alloc(256);

    size_t need = (size_t)(p - (char*)d_ws);
    if (ws_size < need) {
        fprintf(stderr, "kernel_launch: ws too small (%zu < %zu)\n", ws_size, need);
        return;
    }

    hipMemsetAsync(cnt, 0, 1024, stream);  // cnt, cnt2, cntc, offs

    // Routing (fp32, matches reference top-k exactly) + x bf16 cast
    gate_logits<<<T_TOK / 8, 256, 0, stream>>>(x, Wg, logits, xb);
    gate_topk<<<T_TOK / 256, 256, 0, stream>>>(logits, topkE, topkW, cnt);
    offsets_kernel<<<1, 64, 0, stream>>>(cnt, cntc, offs);
    scatter_kernel<<<Pp / 256, 256, 0, stream>>>(topkE, topkW, cntc, offs, cnt2,
                                                 tokC, wtC, posC);

    // weight transposes+casts (3 dispatches)
    transpose_w13<<<dim3(Hm / 64, Dm / 64, 2 * Em), dim3(64, 4), 0, stream>>>(W1, W3, W13T);
    transpose_w2 <<<dim3(Dm / 64, Hm / 64, Em),     dim3(64, 4), 0, stream>>>(W2, W2T);
    transpose_ws <<<dim3(Dm / 64, Dm / 64, 3),      dim3(64, 4), 0, stream>>>(
        Ws1, Ws3, Ws2, Ws13T, Ws2T);

    // GEMM1 (both paths, fused SwiGLU) -> GEMM2 (both paths) -> combine
    gemm1_merged<<<dim3(8, 512 + T_TOK / 128), 256, 0, stream>>>(
        xb, W13T, Ws13T, cntc, offs, tokC, Hh, HhS);
    gemm2_merged<<<dim3(Dm / 128, 512 + T_TOK / 128), 256, 0, stream>>>(
        Hh, HhS, W2T, Ws2T, cntc, offs, Yc, out);
    combine_kernel<<<T_TOK, 256, 0, stream>>>(Yc, topkW, posC, out);
}

// Round 5
// 477.525 us; speedup vs baseline: 1.4238x; 1.4238x over previous
//
#include <hip/hip_runtime.h>
#include <cstdio>

typedef __bf16 bf16;
typedef __bf16 bf16x8 __attribute__((ext_vector_type(8)));
typedef __bf16 bf16x4 __attribute__((ext_vector_type(4)));
typedef float floatx4 __attribute__((ext_vector_type(4)));

#define T_TOK 4096
#define Dm    1024
#define Hm    512
#define Em    32
#define HsDim 1024   // shared inter dim
#define Pp    16384  // T*K pairs
#define CAP   2048   // per-expert capacity

// ---------------------------------------------------------------- gate ------
// logits[t][e] = x[t][:] . Wg[:][e] in fp32 (must match reference routing).
// 8 tokens/block; also writes the bf16 cast of x (x rows already in LDS).
__global__ __launch_bounds__(256) void gate_logits(
    const float* __restrict__ xf, const float* __restrict__ Wg,
    float* __restrict__ logits, bf16* __restrict__ xb)
{
    __shared__ float xs[8][Dm];        // 32 KB
    __shared__ float wsC[128 * Em];    // 16 KB, natural [d][e] layout
    int tid = threadIdx.x;
    int t0 = blockIdx.x * 8;

    const float4* src = (const float4*)(xf + (size_t)t0 * Dm);
    float4* dst = (float4*)&xs[0][0];
#pragma unroll
    for (int i = 0; i < 8; ++i) dst[tid + i * 256] = src[tid + i * 256];

    int tg = tid >> 5, e = tid & 31;
    float acc = 0.f;
    for (int d0 = 0; d0 < Dm; d0 += 128) {
        __syncthreads();               // covers xs on iter 0, wsC reuse after
        const float4* wg4 = (const float4*)(Wg + (size_t)d0 * Em);
        float4* ws4 = (float4*)wsC;
#pragma unroll
        for (int i = 0; i < 4; ++i) ws4[tid + i * 256] = wg4[tid + i * 256];
        __syncthreads();
#pragma unroll
        for (int d = 0; d < 128; d += 4) {
            float4 xv = *(const float4*)&xs[tg][d0 + d];
            acc = fmaf(xv.x, wsC[(d + 0) * Em + e], acc);
            acc = fmaf(xv.y, wsC[(d + 1) * Em + e], acc);
            acc = fmaf(xv.z, wsC[(d + 2) * Em + e], acc);
            acc = fmaf(xv.w, wsC[(d + 3) * Em + e], acc);
        }
    }
    logits[(size_t)(t0 + tg) * Em + e] = acc;

    // bf16 cast of the 8 staged rows (xs unchanged since load; already synced)
    bf16x4* xbrow = (bf16x4*)(xb + (size_t)t0 * Dm);
    const float4* xsf = (const float4*)&xs[0][0];
#pragma unroll
    for (int i = 0; i < 8; ++i) {
        int idx = tid + i * 256;
        float4 v = xsf[idx];
        bf16x4 o = {(bf16)v.x, (bf16)v.y, (bf16)v.z, (bf16)v.w};
        xbrow[idx] = o;
    }
}

// Per-token softmax + stable top-4 (ties -> lower index, same as lax.top_k).
__global__ __launch_bounds__(256) void gate_topk(
    const float* __restrict__ logits, int* __restrict__ topk_e,
    float* __restrict__ topk_w, int* __restrict__ cnt)
{
    __shared__ int hist[Em];
    int tid = threadIdx.x;
    if (tid < Em) hist[tid] = 0;
    __syncthreads();

    int t = blockIdx.x * 256 + tid;
    float l[Em];
    float M = -3.0e38f;
#pragma unroll
    for (int i = 0; i < 8; ++i) {
        float4 v = *(const float4*)(logits + (size_t)t * Em + i * 4);
        l[i * 4 + 0] = v.x; l[i * 4 + 1] = v.y;
        l[i * 4 + 2] = v.z; l[i * 4 + 3] = v.w;
        M = fmaxf(M, fmaxf(fmaxf(v.x, v.y), fmaxf(v.z, v.w)));
    }
    float sum = 0.f;
#pragma unroll
    for (int i = 0; i < Em; ++i) sum += __expf(l[i] - M);
    float inv = 1.0f / sum;
#pragma unroll
    for (int k = 0; k < 4; ++k) {
        float best = -3.0e38f; int bi = 0;
#pragma unroll
        for (int i = 0; i < Em; ++i)
            if (l[i] > best) { best = l[i]; bi = i; }
        topk_e[t * 4 + k] = bi;
        topk_w[t * 4 + k] = __expf(best - M) * inv;
        atomicAdd(&hist[bi], 1);
#pragma unroll
        for (int i = 0; i < Em; ++i)
            if (i == bi) l[i] = -3.0e38f;
    }
    __syncthreads();
    if (tid < Em) { int h = hist[tid]; if (h) atomicAdd(&cnt[tid], h); }
}

__global__ void offsets_kernel(const int* __restrict__ cnt, int* __restrict__ cntc,
                               int* __restrict__ offs)
{
    if (threadIdx.x == 0) {
        int run = 0;
        for (int e = 0; e < Em; ++e) {
            int c = cnt[e]; if (c > CAP) c = CAP;
            cntc[e] = c; offs[e] = run; run += c;
        }
        offs[Em] = run;
    }
}

// Records pair -> compact-row map (posC, -1 = capacity-dropped).
__global__ void scatter_kernel(const int* __restrict__ topk_e, const float* __restrict__ topk_w,
                               const int* __restrict__ cntc, const int* __restrict__ offs,
                               int* __restrict__ cnt2, int* __restrict__ tok_c,
                               float* __restrict__ wt_c, int* __restrict__ posC)
{
    int p = blockIdx.x * 256 + threadIdx.x;
    if (p >= Pp) return;
    int e = topk_e[p];
    int slot = atomicAdd(&cnt2[e], 1);
    int rc = -1;
    if (slot < cntc[e]) {
        rc = offs[e] + slot;
        tok_c[rc] = p >> 2;
        wt_c[rc] = topk_w[p];
    }
    posC[p] = rc;
}

// ---------------------------------------------------------------- casts -----
// 64x64 tile fp32->bf16 transpose. Block (64,4). Reads 256B/wave contiguous;
// LDS reads 2-way aliased (free per m136).
__device__ __forceinline__ void transpose_tile64(
    const float* __restrict__ src, bf16* __restrict__ dst, int R, int Cc)
{
    __shared__ float t[64][65];
    int r0 = blockIdx.y * 64, c0 = blockIdx.x * 64;
    int tx = threadIdx.x, ty = threadIdx.y;
#pragma unroll
    for (int i = 0; i < 16; ++i) {
        int row = ty + i * 4;
        t[row][tx] = src[(long)(r0 + row) * Cc + (c0 + tx)];
    }
    __syncthreads();
#pragma unroll
    for (int i = 0; i < 16; ++i) {
        int row = ty + i * 4;
        dst[(long)(c0 + row) * R + (r0 + tx)] = (bf16)t[tx][row];
    }
}

// W1 (z<32) and W3 (z>=32): (Dm x Hm) -> rows [0,512) / [512,1024) of the
// per-expert 1024 x Dm block of W13T.
__global__ __launch_bounds__(256) void transpose_w13(
    const float* __restrict__ W1, const float* __restrict__ W3,
    bf16* __restrict__ W13T)
{
    int z = blockIdx.z;
    int e = z & 31;
    const float* src = (z < 32 ? W1 : W3) + (long)e * Dm * Hm;
    bf16* dst = W13T + (long)e * 2 * Hm * Dm + (z < 32 ? 0 : (long)Hm * Dm);
    transpose_tile64(src, dst, Dm, Hm);
}

// W2[e]: (Hm x Dm) -> (Dm x Hm)
__global__ __launch_bounds__(256) void transpose_w2(
    const float* __restrict__ W2, bf16* __restrict__ W2T)
{
    int e = blockIdx.z;
    transpose_tile64(W2 + (long)e * Hm * Dm, W2T + (long)e * Hm * Dm, Hm, Dm);
}

// Ws1 / Ws3 / Ws2, each (1024 x 1024), selected by z.
__global__ __launch_bounds__(256) void transpose_ws(
    const float* __restrict__ Ws1, const float* __restrict__ Ws3,
    const float* __restrict__ Ws2, bf16* __restrict__ Ws13T,
    bf16* __restrict__ Ws2T)
{
    int z = blockIdx.z;
    const float* src = z == 0 ? Ws1 : (z == 1 ? Ws3 : Ws2);
    bf16* dst = z == 0 ? Ws13T : (z == 1 ? Ws13T + (long)HsDim * Dm : Ws2T);
    transpose_tile64(src, dst, Dm, Dm);
}

// ---------------------------------------------------------------- GEMM ------
// 128x128 tile, BK=64, 4 waves (64x64 each), mfma_f32_16x16x32_bf16,
// global_load_lds width-16, XOR-swizzled LDS chunks.
__device__ __forceinline__ void gload_lds16(const bf16* g, bf16* l)
{
    __builtin_amdgcn_global_load_lds((const __attribute__((address_space(1))) void*)g,
                                     (__attribute__((address_space(3))) void*)l, 16, 0, 0);
}

// Merged GEMM1 (+fused SwiGLU): blockIdx.y < 512 -> routed experts
// (e = y>>4, gathered A rows, W13T, out Hh ld 512, 4 n-tiles);
// y >= 512 -> shared experts (Ws13T, out HhS ld 1024, 8 n-tiles).
// launch_bounds (256,2): (256,3) forced VGPR 108->84 and spilled the
// accumulators to scratch (R4: WRITE_SIZE 368 MB vs 24 MB of stores) — keep 2.
__global__ void __launch_bounds__(256, 2) gemm1_merged(
    const bf16* __restrict__ xb, const bf16* __restrict__ W13T,
    const bf16* __restrict__ Ws13T,
    const int* __restrict__ cntc, const int* __restrict__ offs,
    const int* __restrict__ tok,
    bf16* __restrict__ Hh, bf16* __restrict__ HhS)
{
    __shared__ __align__(16) bf16 As[128 * 64];
    __shared__ __align__(16) bf16 B1[128 * 64];
    __shared__ __align__(16) bf16 B3[128 * 64];

    int y = blockIdx.y, nt = blockIdx.x;
    int mt, mcount, rowbase;
    const bf16* BT;
    bf16* outH;
    int ldo;
    long off3;
    bool gather;
    if (y < 512) {
        if (nt >= 4) return;               // expert N = 512 -> 4 n-tiles
        int e = y >> 4;
        mt = y & 15;
        mcount = cntc[e];
        if (mt * 128 >= mcount) return;
        rowbase = offs[e];
        BT = W13T + (long)e * 2 * Hm * Dm;
        outH = Hh; ldo = Hm; off3 = (long)Hm * Dm;
        gather = true;
    } else {
        mt = y - 512; mcount = T_TOK; rowbase = 0;
        BT = Ws13T;
        outH = HhS; ldo = HsDim; off3 = (long)HsDim * Dm;
        gather = false;
    }

    int tid = threadIdx.x;
    int wave = tid >> 6, lane = tid & 63;
    int wm = wave >> 1, wn = wave & 1;
    int q = lane >> 4, lm = lane & 15;

    floatx4 acc1[4][4] = {};
    floatx4 acc3[4][4] = {};

    const bf16* arow[4];
    const bf16* brow[4];
#pragma unroll
    for (int it = 0; it < 4; ++it) {
        int c = wave * 256 + it * 64 + lane;
        int row = c >> 3;
        int kc = (c & 7) ^ (row & 7);      // XOR swizzle on 16B chunks
        int rl = mt * 128 + row;
        int rr = rl < mcount ? rl : mcount - 1;
        long aoff;
        if (gather) aoff = (long)tok[rowbase + rr] * Dm;
        else        aoff = (long)rr * Dm;
        arow[it] = xb + aoff + kc * 8;
        brow[it] = BT + (long)(nt * 128 + row) * Dm + kc * 8;
    }

    for (int kt = 0; kt < Dm; kt += 64) {
#pragma unroll
        for (int it = 0; it < 4; ++it)
            gload_lds16(arow[it] + kt, As + (wave * 256 + it * 64) * 8);
#pragma unroll
        for (int it = 0; it < 4; ++it)
            gload_lds16(brow[it] + kt, B1 + (wave * 256 + it * 64) * 8);
#pragma unroll
        for (int it = 0; it < 4; ++it)
            gload_lds16(brow[it] + off3 + kt, B3 + (wave * 256 + it * 64) * 8);
        __syncthreads();
#pragma unroll
        for (int kk = 0; kk < 2; ++kk) {
            bf16x8 af[4], b1v[4], b3v[4];
            int j = kk * 4 + q;
#pragma unroll
            for (int i = 0; i < 4; ++i) {
                int row = wm * 64 + i * 16 + lm;
                af[i] = *(const bf16x8*)(As + row * 64 + ((j ^ (row & 7)) * 8));
            }
#pragma unroll
            for (int j2 = 0; j2 < 4; ++j2) {
                int row = wn * 64 + j2 * 16 + lm;
                b1v[j2] = *(const bf16x8*)(B1 + row * 64 + ((j ^ (row & 7)) * 8));
                b3v[j2] = *(const bf16x8*)(B3 + row * 64 + ((j ^ (row & 7)) * 8));
            }
#pragma unroll
            for (int i = 0; i < 4; ++i)
#pragma unroll
                for (int j2 = 0; j2 < 4; ++j2) {
                    acc1[i][j2] = __builtin_amdgcn_mfma_f32_16x16x32_bf16(
                        af[i], b1v[j2], acc1[i][j2], 0, 0, 0);
                    acc3[i][j2] = __builtin_amdgcn_mfma_f32_16x16x32_bf16(
                        af[i], b3v[j2], acc3[i][j2], 0, 0, 0);
                }
        }
        __syncthreads();
    }

    int colbase = nt * 128 + wn * 64;
#pragma unroll
    for (int i = 0; i < 4; ++i) {
        int rloc = wm * 64 + i * 16 + q * 4;
#pragma unroll
        for (int r = 0; r < 4; ++r) {
            int rl = mt * 128 + rloc + r;
            if (rl >= mcount) continue;
#pragma unroll
            for (int j2 = 0; j2 < 4; ++j2) {
                int col = colbase + j2 * 16 + lm;
                float a = acc1[i][j2][r], b = acc3[i][j2][r];
                float sg = 1.0f / (1.0f + __expf(-a));
                outH[(long)(rowbase + rl) * ldo + col] = (bf16)(a * sg * b);
            }
        }
    }
}

// Merged GEMM2: y < 512 -> expert (A=Hh K=512, B=W2T[e], bf16 compact store
// to Yc); y >= 512 -> shared (A=HhS K=1024, B=Ws2T, fp32 store to out).
__global__ void __launch_bounds__(256, 2) gemm2_merged(
    const bf16* __restrict__ Hh, const bf16* __restrict__ HhS,
    const bf16* __restrict__ W2T, const bf16* __restrict__ Ws2T,
    const int* __restrict__ cntc, const int* __restrict__ offs,
    bf16* __restrict__ Yc, float* __restrict__ out)
{
    __shared__ __align__(16) bf16 As[128 * 64];
    __shared__ __align__(16) bf16 Bs[128 * 64];

    int y = blockIdx.y, nt = blockIdx.x;
    int mt, mcount, rowbase, K, lda;
    const bf16* A;
    const bf16* BT;
    bool toBf;
    if (y < 512) {
        int e = y >> 4;
        mt = y & 15;
        mcount = cntc[e];
        if (mt * 128 >= mcount) return;
        rowbase = offs[e];
        A = Hh; lda = Hm; K = Hm;
        BT = W2T + (long)e * Hm * Dm;
        toBf = true;
    } else {
        mt = y - 512; mcount = T_TOK; rowbase = 0;
        A = HhS; lda = HsDim; K = HsDim;
        BT = Ws2T;
        toBf = false;
    }

    int tid = threadIdx.x;
    int wave = tid >> 6, lane = tid & 63;
    int wm = wave >> 1, wn = wave & 1;
    int q = lane >> 4, lm = lane & 15;

    floatx4 acc[4][4] = {};

    const bf16* arow[4];
    const bf16* brow[4];
#pragma unroll
    for (int it = 0; it < 4; ++it) {
        int c = wave * 256 + it * 64 + lane;
        int row = c >> 3;
        int kc = (c & 7) ^ (row & 7);
        int rl = mt * 128 + row;
        int rr = rl < mcount ? rl : mcount - 1;
        arow[it] = A + (long)(rowbase + rr) * lda + kc * 8;
        brow[it] = BT + (long)(nt * 128 + row) * K + kc * 8;
    }

    for (int kt = 0; kt < K; kt += 64) {
#pragma unroll
        for (int it = 0; it < 4; ++it)
            gload_lds16(arow[it] + kt, As + (wave * 256 + it * 64) * 8);
#pragma unroll
        for (int it = 0; it < 4; ++it)
            gload_lds16(brow[it] + kt, Bs + (wave * 256 + it * 64) * 8);
        __syncthreads();
#pragma unroll
        for (int kk = 0; kk < 2; ++kk) {
            bf16x8 af[4], bfv[4];
            int j = kk * 4 + q;
#pragma unroll
            for (int i = 0; i < 4; ++i) {
                int row = wm * 64 + i * 16 + lm;
                af[i] = *(const bf16x8*)(As + row * 64 + ((j ^ (row & 7)) * 8));
            }
#pragma unroll
            for (int j2 = 0; j2 < 4; ++j2) {
                int row = wn * 64 + j2 * 16 + lm;
                bfv[j2] = *(const bf16x8*)(Bs + row * 64 + ((j ^ (row & 7)) * 8));
            }
#pragma unroll
            for (int i = 0; i < 4; ++i)
#pragma unroll
                for (int j2 = 0; j2 < 4; ++j2)
                    acc[i][j2] = __builtin_amdgcn_mfma_f32_16x16x32_bf16(
                        af[i], bfv[j2], acc[i][j2], 0, 0, 0);
        }
        __syncthreads();
    }

    int colbase = nt * 128 + wn * 64;
#pragma unroll
    for (int i = 0; i < 4; ++i) {
        int rloc = wm * 64 + i * 16 + q * 4;
#pragma unroll
        for (int r = 0; r < 4; ++r) {
            int rl = mt * 128 + rloc + r;
            if (rl >= mcount) continue;
#pragma unroll
            for (int j2 = 0; j2 < 4; ++j2) {
                int col = colbase + j2 * 16 + lm;
                float v = acc[i][j2][r];
                if (toBf) Yc[(long)(rowbase + rl) * Dm + col] = (bf16)v;
                else      out[(long)rl * Dm + col] = v;
            }
        }
    }
}

// ------------------------------------------------------------- combine ------
// out[t][:] += sum_k w[t,k] * Yc[posC[t*4+k]][:]  (posC<0 => dropped pair).
__global__ __launch_bounds__(256) void combine_kernel(
    const bf16* __restrict__ Yc, const float* __restrict__ topkW,
    const int* __restrict__ posC, float* __restrict__ out)
{
    __shared__ int   sp[4];
    __shared__ float sw[4];
    int t = blockIdx.x, tid = threadIdx.x;
    if (tid < 4) {
        sp[tid] = posC[t * 4 + tid];
        sw[tid] = topkW[t * 4 + tid];
    }
    __syncthreads();
    int d = tid * 4;
    float4 o = *(float4*)(out + (size_t)t * Dm + d);
#pragma unroll
    for (int k = 0; k < 4; ++k) {
        int rc = sp[k];
        if (rc >= 0) {
            bf16x4 v = *(const bf16x4*)(Yc + (size_t)rc * Dm + d);
            float w = sw[k];
            o.x += w * (float)v[0];
            o.y += w * (float)v[1];
            o.z += w * (float)v[2];
            o.w += w * (float)v[3];
        }
    }
    *(float4*)(out + (size_t)t * Dm + d) = o;
}

// ---------------------------------------------------------------- launch ----
extern "C" void kernel_launch(void* const* d_in, const int* in_sizes, int n_in,
                              void* d_out, int out_size, void* d_ws, size_t ws_size,
                              hipStream_t stream)
{
    const float* x   = (const float*)d_in[0];
    const float* Wg  = (const float*)d_in[1];
    const float* W1  = (const float*)d_in[2];
    const float* W2  = (const float*)d_in[3];
    const float* W3  = (const float*)d_in[4];
    const float* Ws1 = (const float*)d_in[5];
    const float* Ws2 = (const float*)d_in[6];
    const float* Ws3 = (const float*)d_in[7];
    float* out = (float*)d_out;

    char* p = (char*)d_ws;
    auto alloc = [&](size_t bytes) {
        char* r = p; p += (bytes + 255) & ~(size_t)255; return r;
    };
    bf16*  xb    = (bf16*)alloc((size_t)T_TOK * Dm * 2);
    bf16*  W13T  = (bf16*)alloc((size_t)Em * 2 * Hm * Dm * 2);
    bf16*  W2T   = (bf16*)alloc((size_t)Em * Dm * Hm * 2);
    bf16*  Ws13T = (bf16*)alloc((size_t)2 * HsDim * Dm * 2);
    bf16*  Ws2T  = (bf16*)alloc((size_t)Dm * HsDim * 2);
    bf16*  Yc    = (bf16*)alloc((size_t)Pp * Dm * 2);      // expert GEMM2 compact out
    bf16*  Hh    = (bf16*)alloc((size_t)Pp * Hm * 2);      // expert hidden (compact)
    bf16*  HhS   = (bf16*)alloc((size_t)T_TOK * HsDim * 2);// shared hidden
    float* logits= (float*)alloc((size_t)T_TOK * Em * 4);
    int*   topkE = (int*)alloc(Pp * 4);
    float* topkW = (float*)alloc(Pp * 4);
    int*   tokC  = (int*)alloc(Pp * 4);
    float* wtC   = (float*)alloc(Pp * 4);
    int*   posC  = (int*)alloc(Pp * 4);
    int*   cnt   = (int*)alloc(128);
    int*   cnt2  = (int*)alloc(128);
    int*   cntc  = (int*)alloc(128);
    int*   offs  = (int*)alloc(256);

    size_t need = (size_t)(p - (char*)d_ws);
    if (ws_size < need) {
        fprintf(stderr, "kernel_launch: ws too small (%zu < %zu)\n", ws_size, need);
        return;
    }

    hipMemsetAsync(cnt, 0, 1024, stream);  // cnt, cnt2, cntc, offs

    // Routing (fp32, matches reference top-k exactly) + x bf16 cast
    gate_logits<<<T_TOK / 8, 256, 0, stream>>>(x, Wg, logits, xb);
    gate_topk<<<T_TOK / 256, 256, 0, stream>>>(logits, topkE, topkW, cnt);
    offsets_kernel<<<1, 64, 0, stream>>>(cnt, cntc, offs);
    scatter_kernel<<<Pp / 256, 256, 0, stream>>>(topkE, topkW, cntc, offs, cnt2,
                                                 tokC, wtC, posC);

    // weight transposes+casts (3 dispatches)
    transpose_w13<<<dim3(Hm / 64, Dm / 64, 2 * Em), dim3(64, 4), 0, stream>>>(W1, W3, W13T);
    transpose_w2 <<<dim3(Dm / 64, Hm / 64, Em),     dim3(64, 4), 0, stream>>>(W2, W2T);
    transpose_ws <<<dim3(Dm / 64, Dm / 64, 3),      dim3(64, 4), 0, stream>>>(
        Ws1, Ws3, Ws2, Ws13T, Ws2T);

    // GEMM1 (both paths, fused SwiGLU) -> GEMM2 (both paths) -> combine
    gemm1_merged<<<dim3(8, 512 + T_TOK / 128), 256, 0, stream>>>(
        xb, W13T, Ws13T, cntc, offs, tokC, Hh, HhS);
    gemm2_merged<<<dim3(Dm / 128, 512 + T_TOK / 128), 256, 0, stream>>>(
        Hh, HhS, W2T, Ws2T, cntc, offs, Yc, out);
    combine_kernel<<<T_TOK, 256, 0, stream>>>(Yc, topkW, posC, out);
}